// Round 22
// baseline (346.920 us; speedup 1.0000x reference)
//
#include <hip/hip_runtime.h>

#define B_ 256
#define T_ 500
#define N_ 256
#define BN_ 65536            // B_*N_
#define STP_ 196608          // 3*B_*N_ (states per-t stride)
#define TW 64                // t-window per chunk
#define NCHUNK 8             // ceil(500/64)
#define NTHR 512

// Soft barrier: LDS-visibility sync without vmcnt(0) store drain (stores have
// no in-kernel consumer). sched_barrier fences per rule #18.
#define SOFT_BAR() do {                                   \
    __builtin_amdgcn_sched_barrier(0);                    \
    asm volatile("s_waitcnt lgkmcnt(0)" ::: "memory");    \
    __builtin_amdgcn_s_barrier();                         \
    __builtin_amdgcn_sched_barrier(0);                    \
} while (0)

// ---------------------------------------------------------------------------
// Fused GEMM + Izhikevich scan, chunk-PIPELINED, 512 threads (2 waves/SIMD).
// R21 (339 us) + bank-optimal 8x4 microtile: wave w owns t-rows 8w..8w+7,
// lane owns n-cols 4*lane..4*lane+3. Per kk per wave: A = 2 single-address
// BROADCAST b128 (conflict-free), B = 1 dense full-row b128 (perfectly
// sequential) -- vs R21's 4x8 whose 2-addr A + half-duplicated B produced
// 4.26M bank-conflict cycles. FMAs/thread/kk unchanged (32); k-chain per
// output ascending 0..255 == R17/R21 -> bit-identical I.
// Scan: tid<256, R14-PINNED fmaf text, 2 steps interleaved per ks (R17).
// ---------------------------------------------------------------------------
__global__ __launch_bounds__(NTHR)
void fused_snn_kernel(const float* __restrict__ X, const float* __restrict__ W1,
                      float* __restrict__ out_s, float* __restrict__ states,
                      float* __restrict__ out_dec,
                      const float* __restrict__ st_snn, const float* __restrict__ st_li,
                      const float* __restrict__ W2,
                      const float* __restrict__ pa, const float* __restrict__ pb,
                      const float* __restrict__ pc, const float* __restrict__ pd,
                      const float* __restrict__ pv0, const float* __restrict__ pv1,
                      const float* __restrict__ pv2, const float* __restrict__ ptau,
                      const float* __restrict__ pth, const float* __restrict__ pleak) {
    __shared__ float Xl[TW * 256];              // 64 KB: X chunk c, [k][t]
    __shared__ float Il[TW * 256];              // 64 KB: I chunk c-1, [t][n]
    __shared__ float Ws[2][8 * 256];            // 16 KB: W1t BK=8 slice dbuf
    __shared__ unsigned long long dotm[T_][4];  // 16000 B: per-wave spike masks

    const int bb   = blockIdx.x;
    const int tid  = threadIdx.x;
    const int w    = tid >> 6;           // wave (0..7); scan uses 0..3
    const int lane = tid & 63;
    const int pn   = tid & 255;
    const int boff = bb * 256 + pn;

    // scan per-thread state & params (used by tid<256 only)
    float v = st_snn[boff];
    float u = st_snn[BN_ + boff];
    const float b_   = pb[pn];
    const float c_   = pc[pn];
    const float d_   = pd[pn];
    const float v0_  = pv0[pn];
    const float v1_  = pv1[pn];
    const float v2_  = pv2[pn];
    const float coef = (1.0f / ptau[pn]) * pa[pn];   // (DT/tau_u)*a, DT=1
    const float th_  = pth[pn];

    // GEMM microtile: wave w owns t-rows 8w..8w+7; lane owns n-cols 4*lane..+3
    const int tg8 = w << 3;              // t rows tg8..tg8+7 (wave-uniform!)
    const int h4  = lane << 2;           // n cols h4..h4+3 (dense across wave)

    const float* Xb = X + (size_t)bb * (T_ * 256);
    const int tl = tid & 63;             // X-stage t_loc
    const int wq = (tid >> 6) << 2;      // X-stage k sub-quad (k = wq + 32r)

    // W-stage map: thread covers row wn, k sub-quad wk of each slice
    const int wn = tid >> 1;             // 0..255
    const int wk = (tid & 1) << 2;       // 0 or 4

    // W slice 0 (k wk..wk+3 of row wn) held permanently in regs
    const float4 z0 = *(const float4*)(W1 + (size_t)wn * 256 + wk);

    // stage X chunk 0 (valid=64) and W slice 0
    float4 ra[8];
    {
        const float* Xrow = Xb + (size_t)tl * 256;
#pragma unroll
        for (int r = 0; r < 8; ++r)
            ra[r] = *(const float4*)(Xrow + wq + (r << 5));
    }
#pragma unroll
    for (int r = 0; r < 8; ++r) {
        const int k = wq + (r << 5);
        Xl[(k + 0) * 64 + tl] = ra[r].x;
        Xl[(k + 1) * 64 + tl] = ra[r].y;
        Xl[(k + 2) * 64 + tl] = ra[r].z;
        Xl[(k + 3) * 64 + tl] = ra[r].w;
    }
    {
        float* Wd = &Ws[0][0];
        Wd[(wk + 0) * 256 + wn] = z0.x;
        Wd[(wk + 1) * 256 + wn] = z0.y;
        Wd[(wk + 2) * 256 + wn] = z0.z;
        Wd[(wk + 3) * 256 + wn] = z0.w;
    }
    SOFT_BAR();

    float Inx = 0.f;                     // scan I-prefetch register

    for (int cc = 0; cc < NCHUNK; ++cc) {
        const int tb = (cc - 1) * TW;    // scan chunk base (used when cc>0)

        float acc[8][4];
#pragma unroll
        for (int i = 0; i < 8; ++i)
#pragma unroll
            for (int j = 0; j < 4; ++j) acc[i][j] = 0.f;

        for (int ks = 0; ks < 32; ++ks) {
            float4 q0;
            if (ks < 31) {               // next W slice quad from L2
                q0 = *(const float4*)(W1 + (size_t)wn * 256 + (ks + 1) * 8 + wk);
            }
            if (ks == 24 && cc + 1 < NCHUNK) {   // issue next-chunk X loads
                const int t0n    = (cc + 1) * TW;
                const int validn = (T_ - t0n < TW) ? (T_ - t0n) : TW;
                const int tsrc   = t0n + ((tl < validn) ? tl : (validn - 1));
                const float* Xrow = Xb + (size_t)tsrc * 256;
#pragma unroll
                for (int r = 0; r < 8; ++r)
                    ra[r] = *(const float4*)(Xrow + wq + (r << 5));
            }
            const float* Wc = &Ws[ks & 1][0];
            const int kbase = ks << 3;
#pragma unroll
            for (int kk = 0; kk < 8; ++kk) {
                // A: wave-uniform address -> 2 broadcast b128 (conflict-free)
                const float4 a0 = *(const float4*)&Xl[(kbase + kk) * 64 + tg8];
                const float4 a1 = *(const float4*)&Xl[(kbase + kk) * 64 + tg8 + 4];
                // B: dense full-row b128 (lane L -> cols 4L..4L+3)
                const float4 b0 = *(const float4*)&Wc[kk * 256 + h4];
                const float avr[8] = {a0.x, a0.y, a0.z, a0.w, a1.x, a1.y, a1.z, a1.w};
                const float bvr[4] = {b0.x, b0.y, b0.z, b0.w};
#pragma unroll
                for (int i = 0; i < 8; ++i)
#pragma unroll
                    for (int j = 0; j < 4; ++j)
                        acc[i][j] += avr[i] * bvr[j];
            }
            // interleaved scan: 2 steps of chunk cc-1 (waves 0-3 only)
            if (cc > 0 && tid < 256) {
#pragma unroll
                for (int e = 0; e < 2; ++e) {
                    const int q = (ks << 1) + e;
                    const float Icur = Inx;
                    if (q + 1 < TW) Inx = Il[(q + 1) * 256 + pn];
                    const int t = tb + q;
                    const size_t pbase = (size_t)t * STP_ + boff;

                    // canonical explicit-fma form (pinned, R14 verbatim):
                    const float m1 = v2_ * v;
                    const float t2 = v1_ * v;
                    const float P  = __builtin_fmaf(m1, v, t2);
                    const float Q  = (P + v0_) - u;
                    const float vm = v + (Q + Icur);
                    const float tb2 = __builtin_fmaf(b_, v, -u);
                    const float um = __builtin_fmaf(coef, tb2, u);

                    const bool  sp = (vm - th_) > 0.f;
                    const float s  = sp ? 1.f : 0.f;
                    v = sp ? c_ : vm;        // == vm*(1-s)+s*c exactly
                    u = sp ? (um + d_) : um; // == um + s*d

                    states[pbase]           = v;
                    states[pbase + BN_]     = u;
                    states[pbase + 2 * BN_] = s;
                    out_s[(size_t)t * BN_ + boff] = s;

                    const unsigned long long mset = __ballot(sp);
                    if (lane == 0) dotm[t][w] = mset;
                }
            }
            if (ks < 31) {               // write next W slice after FMAs
                float* Wd = &Ws[(ks + 1) & 1][0];
                Wd[(wk + 0) * 256 + wn] = q0.x;
                Wd[(wk + 1) * 256 + wn] = q0.y;
                Wd[(wk + 2) * 256 + wn] = q0.z;
                Wd[(wk + 3) * 256 + wn] = q0.w;
            }
            SOFT_BAR();
        }

        // chunk end: acc -> Il (scan of cc-1 fully consumed Il; barrier above)
#pragma unroll
        for (int i = 0; i < 8; ++i) {
            const int t = tg8 + i;
            *(float4*)&Il[t * 256 + h4] =
                make_float4(acc[i][0], acc[i][1], acc[i][2], acc[i][3]);
        }
        if (cc + 1 < NCHUNK) {           // next chunk's X (regs, issued ks=24)
#pragma unroll
            for (int r = 0; r < 8; ++r) {
                const int k = wq + (r << 5);
                Xl[(k + 0) * 64 + tl] = ra[r].x;
                Xl[(k + 1) * 64 + tl] = ra[r].y;
                Xl[(k + 2) * 64 + tl] = ra[r].z;
                Xl[(k + 3) * 64 + tl] = ra[r].w;
            }
            float* Wd = &Ws[0][0];       // restage W slice 0 from held regs
            Wd[(wk + 0) * 256 + wn] = z0.x;
            Wd[(wk + 1) * 256 + wn] = z0.y;
            Wd[(wk + 2) * 256 + wn] = z0.z;
            Wd[(wk + 3) * 256 + wn] = z0.w;
        }
        SOFT_BAR();
        Inx = Il[pn];                    // prefetch first I of chunk cc's scan
    }

    // epilogue: scan chunk 7 (52 steps), not overlapped (waves 0-3)
    if (tid < 256) {
        const int tbE = 7 * TW;          // 448
        for (int q = 0; q < 52; ++q) {
            const float Icur = Inx;
            if (q + 1 < 52) Inx = Il[(q + 1) * 256 + pn];
            const int t = tbE + q;
            const size_t pbase = (size_t)t * STP_ + boff;

            const float m1 = v2_ * v;
            const float t2 = v1_ * v;
            const float P  = __builtin_fmaf(m1, v, t2);
            const float Q  = (P + v0_) - u;
            const float vm = v + (Q + Icur);
            const float tb2 = __builtin_fmaf(b_, v, -u);
            const float um = __builtin_fmaf(coef, tb2, u);

            const bool  sp = (vm - th_) > 0.f;
            const float s  = sp ? 1.f : 0.f;
            v = sp ? c_ : vm;
            u = sp ? (um + d_) : um;

            states[pbase]           = v;
            states[pbase + BN_]     = u;
            states[pbase + 2 * BN_] = s;
            out_s[(size_t)t * BN_ + boff] = s;

            const unsigned long long mset = __ballot(sp);
            if (lane == 0) dotm[t][w] = mset;
        }
    }
    __syncthreads();                     // dotm complete

    // masks -> dots (w2l/dotf overlay on dead Ws region: 256+2000 <= 4096 floats)
    float* scr  = &Ws[0][0];
    float* w2l  = scr;                   // [256]
    float* dotf = scr + 256;             // [500][4]
    if (tid < 256) w2l[tid] = W2[tid];
    __syncthreads();
    for (int p = tid; p < T_ * 4; p += NTHR) {
        const int t  = p >> 2;
        const int ww = p & 3;
        unsigned long long m = dotm[t][ww];
        const float* wl = &w2l[ww << 6];
        float sum = 0.f;
        while (m) {
            const int i = __builtin_ctzll(m);
            sum += wl[i];
            m &= (m - 1);
        }
        dotf[t * 4 + ww] = sum;
    }
    __syncthreads();

    if (tid == 0) {
        const float lk_  = pleak[0];
        const float olk_ = 1.0f - lk_;
        float li = st_li[bb];
        for (int t = 0; t < T_; ++t) {
            const float dot = (dotf[t*4+0] + dotf[t*4+1]) + (dotf[t*4+2] + dotf[t*4+3]);
            li = lk_ * li + olk_ * dot;
            out_dec[(size_t)t * 256 + bb] = li;
        }
    }
}

// ---------------------------------------------------------------------------
extern "C" void kernel_launch(void* const* d_in, const int* in_sizes, int n_in,
                              void* d_out, int out_size, void* d_ws, size_t ws_size,
                              hipStream_t stream) {
    const float* input  = (const float*)d_in[0];   // [B,T,N]
    const float* st_snn = (const float*)d_in[1];   // [3,B,N]
    const float* st_li  = (const float*)d_in[2];   // [B,1]
    const float* W1     = (const float*)d_in[3];   // [N,N]
    const float* W2     = (const float*)d_in[4];   // [1,N]
    const float* pa     = (const float*)d_in[5];
    const float* pb     = (const float*)d_in[6];
    const float* pc     = (const float*)d_in[7];
    const float* pd     = (const float*)d_in[8];
    const float* pv0    = (const float*)d_in[9];
    const float* pv1    = (const float*)d_in[10];
    const float* pv2    = (const float*)d_in[11];
    const float* ptau   = (const float*)d_in[12];
    const float* pth    = (const float*)d_in[13];
    const float* pleak  = (const float*)d_in[14];

    float* out        = (float*)d_out;
    float* out_s      = out;                                        // [500,256,256]
    float* out_states = out + (size_t)T_ * BN_;                     // [500,3,256,256]
    float* out_dec    = out + (size_t)T_ * BN_ + (size_t)T_ * STP_; // [500,256]

    fused_snn_kernel<<<dim3(B_), dim3(NTHR), 0, stream>>>(
        input, W1, out_s, out_states, out_dec, st_snn, st_li, W2,
        pa, pb, pc, pd, pv0, pv1, pv2, ptau, pth, pleak);
}